// Round 7
// baseline (255.308 us; speedup 1.0000x reference)
//
#include <hip/hip_runtime.h>

// CAM module: split x into bf16 hi/lo; energy = q qT (bf16x3, symmetric tiles,
// BK=32 dbuf global_load_lds); transpose xh -> xt [n][c] (reusing xl buffer);
// softmin -> bf16 attn; out = gamma*(attn q) + x (energy-style gload_lds GEMM).
// B=16, C=512, N=64*64=4096

#define BATCH 16
#define CCH   512
#define NSP   4096

typedef __attribute__((ext_vector_type(8))) short bfx8;
typedef __attribute__((ext_vector_type(4))) short bfx4;
typedef __attribute__((ext_vector_type(4))) float fx4;
typedef __attribute__((ext_vector_type(2))) float fx2;

__device__ __forceinline__ short f2bf(float v) {
    union { float f; unsigned u; } a; a.f = v;
    unsigned r = a.u + 0x7fffu + ((a.u >> 16) & 1u);   // RNE
    return (short)(r >> 16);
}
__device__ __forceinline__ float bf2f(short s) {
    union { unsigned u; float f; } a; a.u = ((unsigned)(unsigned short)s) << 16;
    return a.f;
}

// async global(16B/lane) -> LDS (wave-uniform base + lane*16)
__device__ __forceinline__ void gload16(const short* g, short* l) {
    __builtin_amdgcn_global_load_lds((const __attribute__((address_space(1))) void*)g,
                                     (__attribute__((address_space(3))) void*)l, 16, 0, 0);
}

// ---------------- Kernel 0: split x -> xh (RNE bf16) + xl (residual bf16) ----------------
__global__ __launch_bounds__(256) void split_kernel(const float* __restrict__ x,
                                                    short* __restrict__ xh,
                                                    short* __restrict__ xl) {
    size_t stride = (size_t)gridDim.x * 256;
    size_t total8 = (size_t)BATCH * CCH * NSP / 8;
    for (size_t u = (size_t)blockIdx.x * 256 + threadIdx.x; u < total8; u += stride) {
        size_t i = u * 8;
        fx4 a = *(const fx4*)(x + i);
        fx4 b = *(const fx4*)(x + i + 4);
        bfx8 h, l;
#pragma unroll
        for (int e = 0; e < 4; ++e) {
            short ha = f2bf(a[e]); h[e]     = ha; l[e]     = f2bf(a[e] - bf2f(ha));
            short hb = f2bf(b[e]); h[e + 4] = hb; l[e + 4] = f2bf(b[e] - bf2f(hb));
        }
        *(bfx8*)(xh + i) = h;
        *(bfx8*)(xl + i) = l;
    }
}

// ---------------- Kernel 1: energy = q qT, bf16x3, symmetric tiles ----------------
// 64x64 tile, 4 waves (32x32 each), BK=32, LDS 32 KiB dbuf. (verified 0 conflicts)
__global__ __launch_bounds__(256) void energy_kernel(const short* __restrict__ xh,
                                                     const short* __restrict__ xl,
                                                     float* __restrict__ energy) {
    int orig = blockIdx.x;
    int wgid = (orig & 7) * 72 + (orig >> 3);   // 576 = 8 xcds x 72
    int b = wgid / 36;
    int t = wgid % 36;
    int ti = 0, rem = t;
    while (rem >= 8 - ti) { rem -= 8 - ti; ++ti; }
    int tj = ti + rem;
    int c0 = ti * 64, d0 = tj * 64;
    bool diag = (ti == tj);
    const short* qh = xh + (size_t)b * CCH * NSP;
    const short* ql = xl + (size_t)b * CCH * NSP;

    __shared__ short S[2][4][64][32];   // [buf][Ah,Al,Bh,Bl][row][k]  = 32 KiB

    int tid  = threadIdx.x;
    int lane = tid & 63;
    int w    = tid >> 6;
    int wr   = (w >> 1) * 32;
    int wc   = (w & 1) * 32;

    int rb   = w * 16;
    int srow = lane >> 2;                       // 0..15
    int gch  = (lane & 3) ^ ((lane >> 3) & 3);  // pre-swizzled source chunk

    auto STAGE = [&](int buf, int kt) {
        size_t koff = (size_t)kt * 32 + gch * 8;
        gload16(qh + (size_t)(c0 + rb + srow) * NSP + koff, &S[buf][0][rb][0]);
        gload16(ql + (size_t)(c0 + rb + srow) * NSP + koff, &S[buf][1][rb][0]);
        if (!diag) {
            gload16(qh + (size_t)(d0 + rb + srow) * NSP + koff, &S[buf][2][rb][0]);
            gload16(ql + (size_t)(d0 + rb + srow) * NSP + koff, &S[buf][3][rb][0]);
        }
    };

    fx4 acc[2][2];
#pragma unroll
    for (int i = 0; i < 2; i++)
#pragma unroll
        for (int j = 0; j < 2; j++) acc[i][j] = (fx4)(0.0f);

    STAGE(0, 0);
    __syncthreads();

    const char* Sb = (const char*)&S[0][0][0][0];
    const int bmH = diag ? 0 : 2, bmL = diag ? 1 : 3;
    int h = lane >> 4;
    int cur = 0;
    const int NT = NSP / 32;
    for (int kt = 0; kt < NT; ++kt) {
        bfx8 ah_[2], al_[2], bh_[2], bl_[2];
        const char* Sc = Sb + cur * (4 * 64 * 64);
#pragma unroll
        for (int mi = 0; mi < 2; ++mi) {
            int r  = wr + mi * 16 + (lane & 15);
            int bo = r * 64 + ((h ^ ((r >> 1) & 3)) << 4);
            ah_[mi] = *(const bfx8*)(Sc + 0 * 4096 + bo);
            al_[mi] = *(const bfx8*)(Sc + 1 * 4096 + bo);
        }
#pragma unroll
        for (int ni = 0; ni < 2; ++ni) {
            int r  = wc + ni * 16 + (lane & 15);
            int bo = r * 64 + ((h ^ ((r >> 1) & 3)) << 4);
            bh_[ni] = *(const bfx8*)(Sc + bmH * 4096 + bo);
            bl_[ni] = *(const bfx8*)(Sc + bmL * 4096 + bo);
        }
        if (kt + 1 < NT) STAGE(cur ^ 1, kt + 1);
#pragma unroll
        for (int mi = 0; mi < 2; ++mi)
#pragma unroll
            for (int ni = 0; ni < 2; ++ni) {
                acc[mi][ni] = __builtin_amdgcn_mfma_f32_16x16x32_bf16(ah_[mi], bh_[ni], acc[mi][ni], 0, 0, 0);
                acc[mi][ni] = __builtin_amdgcn_mfma_f32_16x16x32_bf16(ah_[mi], bl_[ni], acc[mi][ni], 0, 0, 0);
                acc[mi][ni] = __builtin_amdgcn_mfma_f32_16x16x32_bf16(al_[mi], bh_[ni], acc[mi][ni], 0, 0, 0);
            }
        __syncthreads();
        cur ^= 1;
    }

    int colw = lane & 15;
    int rowg = (lane >> 4) * 4;
#pragma unroll
    for (int mi = 0; mi < 2; ++mi)
#pragma unroll
        for (int ni = 0; ni < 2; ++ni) {
            int cb = c0 + wr + mi * 16 + rowg;
            int d  = d0 + wc + ni * 16 + colw;
#pragma unroll
            for (int r = 0; r < 4; ++r) {
                int c = cb + r;
                float v = acc[mi][ni][r];
                energy[((size_t)b * CCH + c) * CCH + d] = v;
                if (!diag)
                    energy[((size_t)b * CCH + d) * CCH + c] = v;
            }
        }
}

// ---------------- Kernel 1.5: transpose xh[b][c][n] -> xt[b][n][c] (bf16) ----------------
// 64n x 64c tile. Gather u32 col-pairs (coalesced 128B segments) -> swizzled LDS rows
// -> coalesced row writes. Chunk swizzle slot = ch ^ ((n>>1)&7); all phases <=2 lanes/bank.
__global__ __launch_bounds__(256) void transpose_kernel(const short* __restrict__ xh,
                                                        short* __restrict__ xt) {
    int blk = blockIdx.x;              // 16 * 8 * 64 = 8192
    int b  = blk >> 9;
    int t  = blk & 511;
    int ct = t >> 6;                   // c-tile 0..7
    int nt = t & 63;                   // n-tile 0..63
    int c0 = ct * 64, n0 = nt * 64;
    const short* src = xh + (size_t)b * CCH * NSP;
    short*       dst = xt + (size_t)b * NSP * CCH;

    __shared__ short Lt[64][64];       // [n][c], 128B rows, swizzled 16B chunks

    int tid = threadIdx.x;
    int p  = tid & 31;                 // col-pair: n = 2p, 2p+1
    int dr = tid >> 5;                 // c-chunk 0..7

    // gather 8 consecutive c-rows for 2 n-columns
    unsigned wv[8];
    const short* sp = src + (size_t)(c0 + dr * 8) * NSP + n0 + 2 * p;
#pragma unroll
    for (int i = 0; i < 8; ++i) wv[i] = *(const unsigned*)(sp + (size_t)i * NSP);
    bfx8 q0, q1;
#pragma unroll
    for (int i = 0; i < 8; ++i) { q0[i] = (short)(wv[i] & 0xffff); q1[i] = (short)(wv[i] >> 16); }
    int slot = dr ^ (p & 7);           // sw(n) = (n>>1)&7 = p&7 for both n=2p,2p+1
    *(bfx8*)(&Lt[0][0] + (2 * p) * 64 + slot * 8)     = q0;
    *(bfx8*)(&Lt[0][0] + (2 * p + 1) * 64 + slot * 8) = q1;
    __syncthreads();

    // write rows of xt
#pragma unroll
    for (int it = 0; it < 2; ++it) {
        int n  = it * 32 + (tid >> 3);
        int ch = tid & 7;
        bfx8 v = *(const bfx8*)(&Lt[0][0] + n * 64 + (ch ^ ((n >> 1) & 7)) * 8);
        *(bfx8*)(dst + (size_t)(n0 + n) * CCH + c0 + ch * 8) = v;
    }
}

// ---------------- Kernel 2: softmin over rows; writes bf16 attn in-place ----------------
__global__ __launch_bounds__(256) void softmax_kernel(float* __restrict__ energy) {
    size_t row = blockIdx.x;
    float* e = energy + row * CCH;
    int tid = threadIdx.x;
    fx2 v = *(const fx2*)(e + 2 * tid);

    float m = fminf(v[0], v[1]);
#pragma unroll
    for (int off = 32; off; off >>= 1) m = fminf(m, __shfl_xor(m, off));
    __shared__ float redm[4];
    __shared__ float reds[4];
    if ((tid & 63) == 0) redm[tid >> 6] = m;
    __syncthreads();
    m = fminf(fminf(redm[0], redm[1]), fminf(redm[2], redm[3]));

    float w0 = __expf(m - v[0]);
    float w1 = __expf(m - v[1]);
    float s = w0 + w1;
#pragma unroll
    for (int off = 32; off; off >>= 1) s += __shfl_xor(s, off);
    if ((tid & 63) == 0) reds[tid >> 6] = s;
    __syncthreads();
    s = (reds[0] + reds[1]) + (reds[2] + reds[3]);
    float inv = 1.0f / s;
    unsigned uw = ((unsigned)(unsigned short)f2bf(w0 * inv)) |
                  (((unsigned)(unsigned short)f2bf(w1 * inv)) << 16);
    ((unsigned*)e)[tid] = uw;   // safe: all reads completed before barriers
}

// ---------------- Kernel 3: out = gamma * (attn @ q) + x ----------------
// 128x128 tile, BK=32, 4 waves each owning 64x64 (16 MFMA/step). Both A (attn rows)
// and B (xt rows) staged via global_load_lds with pre-swizzled source; LDS dbuf 32 KiB.
// Same swizzle formulas as energy_kernel (measured 0 conflicts).
__global__ __launch_bounds__(256, 3) void out_kernel(const float* __restrict__ x,
                                                     const short* __restrict__ attnb, // 1024-short rows
                                                     const short* __restrict__ xt,    // [n][c] bf16
                                                     const float* __restrict__ gamma,
                                                     float* __restrict__ out) {
    // XCD-chunked swizzle: 2048 blocks = 8 x 256
    int orig = blockIdx.x;
    int blk  = (orig & 7) * 256 + (orig >> 3);
    int b   = blk >> 7;                 // 128 blocks per batch
    int t   = blk & 127;
    int c0  = (t >> 5) * 128;
    int n0  = (t & 31) * 128;
    const float* xb = x + (size_t)b * CCH * NSP;
    const short* ab = attnb + (size_t)b * CCH * 1024;
    const short* qt = xt + (size_t)b * NSP * CCH;

    __shared__ short SA[2][128][32];    // [buf][c-row][k]
    __shared__ short SB[2][128][32];    // [buf][n-row][k]

    int tid  = threadIdx.x;
    int lane = tid & 63;
    int w    = tid >> 6;
    int wr   = (w >> 1) * 64;           // c offset of wave
    int wc   = (w & 1) * 64;            // n offset of wave

    int srow = lane >> 2;                       // 0..15
    int gch  = (lane & 3) ^ ((lane >> 3) & 3);  // pre-swizzled source chunk

    auto STAGE = [&](int buf, int kt) {
#pragma unroll
        for (int hf = 0; hf < 2; ++hf) {
            int rg = hf * 64 + w * 16;          // wave-uniform row group
            gload16(ab + (size_t)(c0 + rg + srow) * 1024 + kt * 32 + gch * 8, &SA[buf][rg][0]);
            gload16(qt + (size_t)(n0 + rg + srow) * 512  + kt * 32 + gch * 8, &SB[buf][rg][0]);
        }
    };

    fx4 acc[4][4];
#pragma unroll
    for (int i = 0; i < 4; i++)
#pragma unroll
        for (int j = 0; j < 4; j++) acc[i][j] = (fx4)(0.0f);

    STAGE(0, 0);
    __syncthreads();

    int h = lane >> 4;
    int cur = 0;
    const int NT = CCH / 32;            // 16
    for (int kt = 0; kt < NT; ++kt) {
        bfx8 af[4], bf[4];
#pragma unroll
        for (int mi = 0; mi < 4; ++mi) {
            int r  = wr + mi * 16 + (lane & 15);
            af[mi] = *(const bfx8*)((const char*)&SA[cur][0][0] + r * 64 + ((h ^ ((r >> 1) & 3)) << 4));
        }
#pragma unroll
        for (int ni = 0; ni < 4; ++ni) {
            int r  = wc + ni * 16 + (lane & 15);
            bf[ni] = *(const bfx8*)((const char*)&SB[cur][0][0] + r * 64 + ((h ^ ((r >> 1) & 3)) << 4));
        }
        if (kt + 1 < NT) STAGE(cur ^ 1, kt + 1);
#pragma unroll
        for (int mi = 0; mi < 4; ++mi)
#pragma unroll
            for (int ni = 0; ni < 4; ++ni)
                acc[mi][ni] = __builtin_amdgcn_mfma_f32_16x16x32_bf16(af[mi], bf[ni], acc[mi][ni], 0, 0, 0);
        __syncthreads();
        cur ^= 1;
    }

    float g = gamma[0];
    int colw = lane & 15;
    int rowg = (lane >> 4) * 4;
#pragma unroll
    for (int mi = 0; mi < 4; ++mi)
#pragma unroll
        for (int ni = 0; ni < 4; ++ni) {
            int n = n0 + wc + ni * 16 + colw;
#pragma unroll
            for (int r = 0; r < 4; ++r) {
                int c = c0 + wr + mi * 16 + rowg + r;
                size_t off = ((size_t)b * CCH + c) * NSP + n;
                out[off] = g * acc[mi][ni][r] + xb[(size_t)c * NSP + n];
            }
        }
}

extern "C" void kernel_launch(void* const* d_in, const int* in_sizes, int n_in,
                              void* d_out, int out_size, void* d_ws, size_t ws_size,
                              hipStream_t stream) {
    (void)in_sizes; (void)n_in; (void)out_size; (void)ws_size;
    const float* x     = (const float*)d_in[0];
    const float* gamma = (const float*)d_in[1];
    float*       out   = (float*)d_out;

    size_t nel  = (size_t)BATCH * CCH * NSP;
    size_t bfsz = nel * sizeof(short);                   // 64 MiB
    short* xhp    = (short*)d_ws;
    short* xlp    = (short*)((char*)d_ws + bfsz);        // xl; reused as xt after energy
    float* energy = (float*)((char*)d_ws + 2 * bfsz);    // 16 MiB

    split_kernel     <<<2048, 256, 0, stream>>>(x, xhp, xlp);
    energy_kernel    <<<BATCH * 36, 256, 0, stream>>>(xhp, xlp, energy);
    transpose_kernel <<<BATCH * 512, 256, 0, stream>>>(xhp, xlp);       // xl -> xt
    softmax_kernel   <<<BATCH * CCH, 256, 0, stream>>>(energy);
    out_kernel       <<<BATCH * 128, 256, 0, stream>>>(x, (const short*)energy, xlp, gamma, out);
}